// Round 16
// baseline (3576.743 us; speedup 1.0000x reference)
//
#include <hip/hip_runtime.h>
#include <hip/hip_cooperative_groups.h>
namespace cg = cooperative_groups;

typedef unsigned short u16;
typedef __bf16 bf16x8 __attribute__((ext_vector_type(8)));
typedef float f32x4 __attribute__((ext_vector_type(4)));
typedef float f32x4v __attribute__((ext_vector_type(4)));
typedef u16 u16x4 __attribute__((ext_vector_type(4)));

__device__ __forceinline__ float bf2f(u16 u) {
    unsigned x = ((unsigned)u) << 16;
    return __builtin_bit_cast(float, x);
}
__device__ __forceinline__ u16 f2bf(float f) {
    unsigned x = __builtin_bit_cast(unsigned, f);
    unsigned r = (x + 0x7FFFu + ((x >> 16) & 1u)) >> 16;
    return (u16)r;
}

// ------- f32 -> bf16 conversion (chunk-strided dest; linear if chunk==n) ----
__global__ __launch_bounds__(256) void cvt_kernel(const float* __restrict__ in,
                                                  u16* __restrict__ out, long n,
                                                  long chunk, long stride) {
    for (long i = (long)blockIdx.x * 1024 + (long)threadIdx.x * 4; i < n;
         i += (long)gridDim.x * 1024) {
        f32x4v v = *(const f32x4v*)(in + i);
        u16x4 o;
        o.x = f2bf(v.x); o.y = f2bf(v.y); o.z = f2bf(v.z); o.w = f2bf(v.w);
        long c = i / chunk, rrem = i - c * chunk;
        *(u16x4*)(out + c * stride + rrem) = o;
    }
}

// ---------------- fused qkv bias ----------------
__global__ __launch_bounds__(256) void bias_fuse_kernel(const float* __restrict__ bq,
                                                        const float* __restrict__ bk,
                                                        const float* __restrict__ bv,
                                                        float* __restrict__ dst) {
    int i = blockIdx.x * 256 + threadIdx.x;
    if (i < 6 * 768) {
        int l = i / 768, j = i % 768;
        dst[l * 2304 + j] = bq[i];
        dst[l * 2304 + 768 + j] = bk[i];
        dst[l * 2304 + 1536 + j] = bv[i];
    }
}

// ------- embed + layer-0 ln1 fused: h = tok[x]+pos; a = LN(h) -------
__global__ __launch_bounds__(256) void embed_ln_kernel(
    const int* __restrict__ x, const float* __restrict__ tok,
    const float* __restrict__ pos, float* __restrict__ h,
    const float* __restrict__ w, const float* __restrict__ b,
    u16* __restrict__ out) {
    __shared__ float red[4];
    int row = blockIdx.x;
    int t = row & 1023;
    long id = x[row];
    const float* te = tok + id * 768L;
    const float* pe = pos + (long)t * 768L;
    float* hr = h + (long)row * 768L;
    int tid = threadIdx.x, lane = tid & 63, wid = tid >> 6;
    float v0 = te[tid] + pe[tid];
    float v1 = te[tid + 256] + pe[tid + 256];
    float v2 = te[tid + 512] + pe[tid + 512];
    hr[tid] = v0; hr[tid + 256] = v1; hr[tid + 512] = v2;
    float s = v0 + v1 + v2;
    for (int o = 32; o; o >>= 1) s += __shfl_xor(s, o);
    if (lane == 0) red[wid] = s;
    __syncthreads();
    float mean = (red[0] + red[1] + red[2] + red[3]) * (1.f / 768.f);
    __syncthreads();
    float d0 = v0 - mean, d1 = v1 - mean, d2 = v2 - mean;
    float q = d0 * d0 + d1 * d1 + d2 * d2;
    for (int o = 32; o; o >>= 1) q += __shfl_xor(q, o);
    if (lane == 0) red[wid] = q;
    __syncthreads();
    float var = (red[0] + red[1] + red[2] + red[3]) * (1.f / 768.f);
    float rstd = rsqrtf(var + 1e-5f);
    u16* orow = out + (long)row * 768L;
    orow[tid]       = f2bf(d0 * rstd * w[tid]       + b[tid]);
    orow[tid + 256] = f2bf(d1 * rstd * w[tid + 256] + b[tid + 256]);
    orow[tid + 512] = f2bf(d2 * rstd * w[tid + 512] + b[tid + 512]);
}

// ====================== device job bodies (shared by mega+head) =============

// GEMM job: 2-phase dbuf + both-sides swizzle + split-K. EPI: 2 relu(+bias)
// bf16; 5 f32 partials (+slice*partStride); 6 qkv-split (q,k->Cv, v->aux^T).
template <int BM, int BN, int BK, int EPI, int SK>
__device__ __forceinline__ void gemm_job(
    int flat, int nwg, int tid,
    u16* As0, u16* As1, u16* Bs0, u16* Bs1,
    const u16* __restrict__ A, int lda,
    const u16* __restrict__ Bm, int ldb,
    void* __restrict__ Cv, int ldc,
    const float* __restrict__ bias, int Kslice, int gm,
    u16* __restrict__ aux, long partStride) {
    constexpr int CPR = BK / 8;
    constexpr int KH = BK / 32;
    int qq = nwg >> 3, rr = nwg & 7;
    int xcd = flat & 7, wi = flat >> 3;
    int swz = (xcd < rr) ? (xcd * (qq + 1) + wi) : (rr * (qq + 1) + (xcd - rr) * qq + wi);
    int slice = 0, wblk = swz;
    if (SK > 1) { int nbs = nwg / SK; slice = wblk / nbs; wblk -= slice * nbs; }
    int ntile = wblk / gm, mt = wblk - ntile * gm;
    int bm0 = mt * BM, bn0 = ntile * BN;
    long koff = (long)slice * Kslice;
    const u16* Ab = A + (long)bm0 * lda + koff;
    const u16* Bb = Bm + (long)bn0 * ldb + koff;

    int lane = tid & 63, wid = tid >> 6;
    constexpr int WM = BM / 2, WN = BN / 2, MR = WM / 16, NR = WN / 16;
    int wm0 = (wid >> 1) * WM, wn0 = (wid & 1) * WN;

    f32x4 acc[MR][NR];
#pragma unroll
    for (int mi = 0; mi < MR; mi++)
#pragma unroll
        for (int ni = 0; ni < NR; ni++) acc[mi][ni] = 0.f;

    int nt = Kslice / BK;
    auto key = [](int row) { return (BK == 32) ? ((row >> 1) & 3) : (row & 7); };
    auto stage = [&](u16* Asb, u16* Bsb, int k0) {
        constexpr int CA = BM * CPR;
#pragma unroll
        for (int c0 = 0; c0 < CA; c0 += 256) {
            int c = c0 + tid;
            int row = c / CPR, sl = c & (CPR - 1);
            int ks = sl ^ key(row);
            __builtin_amdgcn_global_load_lds(
                (const __attribute__((address_space(1))) unsigned*)(Ab + (long)row * lda + k0 + ks * 8),
                (__attribute__((address_space(3))) unsigned*)(Asb + c * 8), 16, 0, 0);
        }
        constexpr int CB = BN * CPR;
#pragma unroll
        for (int c0 = 0; c0 < CB; c0 += 256) {
            int c = c0 + tid;
            int row = c / CPR, sl = c & (CPR - 1);
            int ks = sl ^ key(row);
            __builtin_amdgcn_global_load_lds(
                (const __attribute__((address_space(1))) unsigned*)(Bb + (long)row * ldb + k0 + ks * 8),
                (__attribute__((address_space(3))) unsigned*)(Bsb + c * 8), 16, 0, 0);
        }
    };

    stage(As0, Bs0, 0);
    __syncthreads();
    int rA = lane & 15, sA = lane >> 4;
    for (int t = 0; t < nt; ++t) {
        u16* Asc = (t & 1) ? As1 : As0;
        u16* Bsc = (t & 1) ? Bs1 : Bs0;
        if (t + 1 < nt) stage((t & 1) ? As0 : As1, (t & 1) ? Bs0 : Bs1, (t + 1) * BK);
        bf16x8 af[MR][KH], bfr[NR][KH];
#pragma unroll
        for (int mi = 0; mi < MR; mi++) {
            int row = wm0 + mi * 16 + rA;
#pragma unroll
            for (int h = 0; h < KH; h++)
                af[mi][h] = *(const bf16x8*)(Asc + row * BK + (((h << 2) + sA) ^ key(row)) * 8);
        }
#pragma unroll
        for (int ni = 0; ni < NR; ni++) {
            int row = wn0 + ni * 16 + rA;
#pragma unroll
            for (int h = 0; h < KH; h++)
                bfr[ni][h] = *(const bf16x8*)(Bsc + row * BK + (((h << 2) + sA) ^ key(row)) * 8);
        }
#pragma unroll
        for (int h = 0; h < KH; h++)
#pragma unroll
            for (int mi = 0; mi < MR; mi++)
#pragma unroll
                for (int ni = 0; ni < NR; ni++)
                    acc[mi][ni] = __builtin_amdgcn_mfma_f32_16x16x32_bf16(
                        af[mi][h], bfr[ni][h], acc[mi][ni], 0, 0, 0);
        __syncthreads();
    }

#pragma unroll
    for (int mi = 0; mi < MR; mi++)
#pragma unroll
        for (int ni = 0; ni < NR; ni++) {
            int gmb = bm0 + wm0 + mi * 16 + ((lane >> 4) << 2);
            int gn = bn0 + wn0 + ni * 16 + (lane & 15);
            if (EPI == 6) {
                if (gn < 1536) {
#pragma unroll
                    for (int j = 0; j < 4; j++)
                        ((u16*)Cv)[(long)(gmb + j) * ldc + gn] =
                            f2bf(acc[mi][ni][j] + bias[gn]);
                } else {
                    u16x4 o;
#pragma unroll
                    for (int j = 0; j < 4; j++) o[j] = f2bf(acc[mi][ni][j] + bias[gn]);
                    int hh = (gn - 1536) >> 6, dk = gn & 63;
                    long off = ((long)((gmb >> 10) * 12 + hh) * 64 + dk) * 1024 + (gmb & 1023);
                    *(u16x4*)(aux + off) = o;
                }
            } else {
#pragma unroll
                for (int j = 0; j < 4; j++) {
                    float v = acc[mi][ni][j];
                    long idx = (long)(gmb + j) * ldc + gn;
                    if (EPI == 2) ((u16*)Cv)[idx] = f2bf(fmaxf(v + bias[gn], 0.f));
                    else ((float*)Cv)[(long)slice * partStride + idx] = v;  // EPI 5
                }
            }
        }
}

// flash attention job (causal, DK=64, K/V double-buffered)
__device__ __forceinline__ void flash_job(
    int job, int tid, u16* lds,
    const u16* __restrict__ qkv, const u16* __restrict__ vT,
    u16* __restrict__ ctx) {
    int z = job >> 4;
    int zb = z / 12, zh = z - zb * 12;
    int qt = 15 - (job & 15);       // big tiles first
    int q0 = qt * 64;
    int lane = tid & 63, wid = tid >> 6;
    int rA = lane & 15, sA = lane >> 4;

    u16* Ks0 = lds;            u16* Ks1 = lds + 4096;
    u16* Vs0 = lds + 8192;     u16* Vs1 = lds + 12288;
    u16* Psw = lds + 16384 + wid * 1024;

    const u16* Qbase = qkv + (long)zb * 1024 * 2304 + zh * 64;
    const u16* Kbase = Qbase + 768;
    const u16* Vbase = vT + (long)z * 64 * 1024;

    bf16x8 aq[2];
    {
        const u16* qrow = Qbase + (long)(q0 + wid * 16 + rA) * 2304;
        aq[0] = *(const bf16x8*)(qrow + sA * 8);
        aq[1] = *(const bf16x8*)(qrow + 32 + sA * 8);
    }

    auto stage = [&](u16* Ksb, u16* Vsb, int kv0) {
#pragma unroll
        for (int c0 = 0; c0 < 512; c0 += 256) {
            int c = c0 + tid;
            int row = c >> 3, half = (c >> 2) & 1, sl = c & 3;
            int ks = sl ^ ((row >> 1) & 3);
            __builtin_amdgcn_global_load_lds(
                (const __attribute__((address_space(1))) unsigned*)(Kbase + (long)(kv0 + row) * 2304 + half * 32 + ks * 8),
                (__attribute__((address_space(3))) unsigned*)(Ksb + c * 8), 16, 0, 0);
        }
#pragma unroll
        for (int c0 = 0; c0 < 512; c0 += 256) {
            int c = c0 + tid;
            int row = c >> 3, half = (c >> 2) & 1, sl = c & 3;
            int ks = sl ^ ((row >> 1) & 3);
            __builtin_amdgcn_global_load_lds(
                (const __attribute__((address_space(1))) unsigned*)(Vbase + (long)row * 1024 + kv0 + half * 32 + ks * 8),
                (__attribute__((address_space(3))) unsigned*)(Vsb + c * 8), 16, 0, 0);
        }
    };

    float m[4], l[4];
    f32x4 acc_o[4];
#pragma unroll
    for (int j = 0; j < 4; j++) { m[j] = -1e30f; l[j] = 0.f; }
#pragma unroll
    for (int nf = 0; nf < 4; nf++) acc_o[nf] = 0.f;

    int grow0 = q0 + wid * 16 + sA * 4;
    int nkv = qt + 1;

    stage(Ks0, Vs0, 0);
    __syncthreads();
    for (int t = 0; t < nkv; ++t) {
        u16* Ksc = (t & 1) ? Ks1 : Ks0;
        u16* Vsc = (t & 1) ? Vs1 : Vs0;
        int kv0 = t * 64;
        if (t + 1 < nkv) stage((t & 1) ? Ks0 : Ks1, (t & 1) ? Vs0 : Vs1, (t + 1) * 64);

        f32x4 s[4];
#pragma unroll
        for (int nf = 0; nf < 4; nf++) s[nf] = 0.f;
        __builtin_amdgcn_s_setprio(1);
#pragma unroll
        for (int h = 0; h < 2; h++)
#pragma unroll
            for (int nf = 0; nf < 4; nf++) {
                int row = nf * 16 + rA;
                bf16x8 bk_ = *(const bf16x8*)(Ksc + row * 64 + h * 32 + ((sA ^ ((row >> 1) & 3))) * 8);
                s[nf] = __builtin_amdgcn_mfma_f32_16x16x32_bf16(aq[h], bk_, s[nf], 0, 0, 0);
            }
        __builtin_amdgcn_s_setprio(0);
#pragma unroll
        for (int nf = 0; nf < 4; nf++) {
            int col = kv0 + nf * 16 + rA;
#pragma unroll
            for (int j = 0; j < 4; j++)
                s[nf][j] = (col <= grow0 + j) ? s[nf][j] * 0.125f : -1e30f;
        }
        float pm[4];
#pragma unroll
        for (int j = 0; j < 4; j++) {
            float v = fmaxf(fmaxf(s[0][j], s[1][j]), fmaxf(s[2][j], s[3][j]));
#pragma unroll
            for (int o = 1; o < 16; o <<= 1) v = fmaxf(v, __shfl_xor(v, o));
            pm[j] = v;
        }
        float esc[4];
#pragma unroll
        for (int j = 0; j < 4; j++) {
            float mn = fmaxf(m[j], pm[j]);
            esc[j] = __expf(m[j] - mn);
            m[j] = mn;
        }
        float ts[4] = {0.f, 0.f, 0.f, 0.f};
#pragma unroll
        for (int nf = 0; nf < 4; nf++) {
            int c = nf * 16 + rA;
            int half = c >> 5, ch = (c >> 3) & 3, e = c & 7;
#pragma unroll
            for (int j = 0; j < 4; j++) {
                float p = __expf(s[nf][j] - m[j]);
                ts[j] += p;
                int r = sA * 4 + j;
                Psw[r * 64 + half * 32 + (ch ^ ((r >> 1) & 3)) * 8 + e] = f2bf(p);
            }
        }
#pragma unroll
        for (int j = 0; j < 4; j++) {
            float v = ts[j];
#pragma unroll
            for (int o = 1; o < 16; o <<= 1) v += __shfl_xor(v, o);
            l[j] = l[j] * esc[j] + v;
        }
#pragma unroll
        for (int nf = 0; nf < 4; nf++)
#pragma unroll
            for (int j = 0; j < 4; j++) acc_o[nf][j] *= esc[j];

        __builtin_amdgcn_s_setprio(1);
#pragma unroll
        for (int h = 0; h < 2; h++) {
            bf16x8 ap = *(const bf16x8*)(Psw + rA * 64 + h * 32 + ((sA ^ ((rA >> 1) & 3))) * 8);
#pragma unroll
            for (int nf = 0; nf < 4; nf++) {
                int row = nf * 16 + rA;
                bf16x8 bv_ = *(const bf16x8*)(Vsc + row * 64 + h * 32 + ((sA ^ ((row >> 1) & 3))) * 8);
                acc_o[nf] = __builtin_amdgcn_mfma_f32_16x16x32_bf16(ap, bv_, acc_o[nf], 0, 0, 0);
            }
        }
        __builtin_amdgcn_s_setprio(0);
        __syncthreads();
    }

    float inv[4];
#pragma unroll
    for (int j = 0; j < 4; j++) inv[j] = 1.f / l[j];
    u16* crow = ctx + ((long)zb * 1024 + q0 + wid * 16) * 768 + zh * 64;
#pragma unroll
    for (int nf = 0; nf < 4; nf++)
#pragma unroll
        for (int j = 0; j < 4; j++)
            crow[(long)(sA * 4 + j) * 768 + nf * 16 + rA] = f2bf(acc_o[nf][j] * inv[j]);
}

// redln job (256 thr, one row): h += sum(partials)+bias; a = LN(h)
__device__ __forceinline__ void redln_row(
    int row, int tid, float* red,
    const float* __restrict__ part, long pstride, int S,
    const float* __restrict__ bias, float* __restrict__ h,
    const float* __restrict__ w, const float* __restrict__ b,
    u16* __restrict__ out) {
    int lane = tid & 63, wid = tid >> 6;
    long base = (long)row * 768;
    float v[3];
#pragma unroll
    for (int j = 0; j < 3; j++) {
        int e = tid + 256 * j;
        float x = h[base + e] + bias[e];
        for (int s = 0; s < S; s++) x += part[(long)s * pstride + base + e];
        v[j] = x;
        h[base + e] = x;
    }
    float s = v[0] + v[1] + v[2];
    for (int o = 32; o; o >>= 1) s += __shfl_xor(s, o);
    if (lane == 0) red[wid] = s;
    __syncthreads();
    float mean = (red[0] + red[1] + red[2] + red[3]) * (1.f / 768.f);
    __syncthreads();
    float d0 = v[0] - mean, d1 = v[1] - mean, d2 = v[2] - mean;
    float q = d0 * d0 + d1 * d1 + d2 * d2;
    for (int o = 32; o; o >>= 1) q += __shfl_xor(q, o);
    if (lane == 0) red[wid] = q;
    __syncthreads();
    float var = (red[0] + red[1] + red[2] + red[3]) * (1.f / 768.f);
    float rstd = rsqrtf(var + 1e-5f);
    u16* orow = out + base;
    orow[tid]       = f2bf(d0 * rstd * w[tid]       + b[tid]);
    orow[tid + 256] = f2bf(d1 * rstd * w[tid + 256] + b[tid + 256]);
    orow[tid + 512] = f2bf(d2 * rstd * w[tid + 512] + b[tid + 512]);
    __syncthreads();  // red[] safe for next row
}

// ================= cooperative 6-layer mega-kernel =================
struct LP {
    const u16* qkvw; const float* qkvbias;
    u16* a; u16* qkvb; u16* vT; u16* ctxb; u16* f1;
    const u16* wo; const u16* w1; const u16* w2;
    const float* bo; const float* b1; const float* b2;
    const float* ln2w; const float* ln2b;
    const float* ln1w; const float* ln1b;
    const float* lnfw; const float* lnfb;
    float* h; float* part;
};

__global__ __launch_bounds__(256, 3) void layers_kernel(LP p) {
    __shared__ u16 lds[24576];   // 48 KB: gemm 64x128x64 union flash union red
    cg::grid_group grid = cg::this_grid();
    int bid = blockIdx.x, tid = threadIdx.x, ng = gridDim.x;
    const long DD = 768L * 768, FD = 3072L * 768, PS = 2048L * 768;
    u16* As0 = lds;                    // 64*64 = 4096
    u16* As1 = lds + 4096;
    u16* Bs0 = lds + 8192;             // 128*64 = 8192
    u16* Bs1 = lds + 16384;

    for (int i = 0; i < 6; ++i) {
        // qkv = a @ qkvw^T + bias ; v -> vT  (576 jobs)
        for (int job = bid; job < 576; job += ng)
            gemm_job<64, 128, 64, 6, 1>(job, 576, tid, As0, As1, Bs0, Bs1,
                p.a, 768, p.qkvw + (long)i * 3 * DD, 768, p.qkvb, 2304,
                p.qkvbias + i * 2304, 768, 32, p.vT, 0);
        __threadfence(); grid.sync();
        // flash (384 jobs)
        for (int job = bid; job < 384; job += ng)
            flash_job(job, tid, lds, p.qkvb, p.vT, p.ctxb);
        __threadfence(); grid.sync();
        // wo split-K=2 -> partials (384 jobs)
        for (int job = bid; job < 384; job += ng)
            gemm_job<64, 128, 64, 5, 2>(job, 384, tid, As0, As1, Bs0, Bs1,
                p.ctxb, 768, p.wo + (long)i * DD, 768, p.part, 768,
                nullptr, 384, 32, nullptr, PS);
        __threadfence(); grid.sync();
        // redln S=2 -> a (ln2)
        for (int row = bid; row < 2048; row += ng)
            redln_row(row, tid, (float*)lds, p.part, PS, 2, p.bo + i * 768,
                      p.h, p.ln2w + i * 768, p.ln2b + i * 768, p.a);
        __threadfence(); grid.sync();
        // ffn1 relu (768 jobs)
        for (int job = bid; job < 768; job += ng)
            gemm_job<64, 128, 64, 2, 1>(job, 768, tid, As0, As1, Bs0, Bs1,
                p.a, 768, p.w1 + (long)i * FD, 768, p.f1, 3072,
                p.b1 + i * 3072, 768, 32, nullptr, 0);
        __threadfence(); grid.sync();
        // ffn2 split-K=4 -> partials (768 jobs)
        for (int job = bid; job < 768; job += ng)
            gemm_job<64, 128, 64, 5, 4>(job, 768, tid, As0, As1, Bs0, Bs1,
                p.f1, 3072, p.w2 + (long)i * FD, 3072, p.part, 768,
                nullptr, 768, 32, nullptr, PS);
        __threadfence(); grid.sync();
        // redln S=4 -> a (next ln1 or lnf)
        {
            const float* w = (i + 1 < 6) ? p.ln1w + (i + 1) * 768 : p.lnfw;
            const float* b = (i + 1 < 6) ? p.ln1b + (i + 1) * 768 : p.lnfb;
            for (int row = bid; row < 2048; row += ng)
                redln_row(row, tid, (float*)lds, p.part, PS, 4, p.b2 + i * 768,
                          p.h, w, b, p.a);
        }
        __threadfence(); grid.sync();
    }
}

// standalone GEMM wrapper (head)
template <int BM, int BN, int BK, int EPI, int SK>
__global__ __launch_bounds__(256) void gemmg_kernel(
    const u16* __restrict__ A, int lda,
    const u16* __restrict__ Bm, int ldb,
    void* __restrict__ Cv, int ldc,
    const float* __restrict__ bias, int Kslice, int gm,
    u16* __restrict__ aux, long partStride) {
    __shared__ u16 lds[2 * BM * BK + 2 * BN * BK];
    gemm_job<BM, BN, BK, EPI, SK>(blockIdx.x, gridDim.x, threadIdx.x,
        lds, lds + BM * BK, lds + 2 * BM * BK, lds + 2 * BM * BK + BN * BK,
        A, lda, Bm, ldb, Cv, ldc, bias, Kslice, gm, aux, partStride);
}

// ---------------- host side ----------------
extern "C" void kernel_launch(void* const* d_in, const int* in_sizes, int n_in,
                              void* d_out, int out_size, void* d_ws, size_t ws_size,
                              hipStream_t stream) {
    const int L = 6, D = 768, F = 3072, T = 1024, V = 32000;
    const int M = 2048;  // B*T
    const int* x = (const int*)d_in[0];
    const float* tok = (const float*)d_in[1];
    const float* pos = (const float*)d_in[2];
    const float* ln1w = (const float*)d_in[3];
    const float* ln1b = (const float*)d_in[4];
    const float* wq = (const float*)d_in[5];
    const float* bq = (const float*)d_in[6];
    const float* wk = (const float*)d_in[7];
    const float* bk = (const float*)d_in[8];
    const float* wv = (const float*)d_in[9];
    const float* bv = (const float*)d_in[10];
    const float* wo = (const float*)d_in[11];
    const float* bo = (const float*)d_in[12];
    const float* ln2w = (const float*)d_in[13];
    const float* ln2b = (const float*)d_in[14];
    const float* w1 = (const float*)d_in[15];
    const float* b1 = (const float*)d_in[16];
    const float* w2 = (const float*)d_in[17];
    const float* b2 = (const float*)d_in[18];
    const float* lnfw = (const float*)d_in[19];
    const float* lnfb = (const float*)d_in[20];
    const float* headw = (const float*)d_in[21];

    char* p = (char*)d_ws;
    auto alloc = [&](size_t bytes) {
        char* r = p;
        p += (bytes + 255) & ~(size_t)255;
        return r;
    };
    const long DD = (long)D * D, FD = (long)F * D;
    const long PS = (long)M * D;
    u16* qkvw_b = (u16*)alloc(L * 3 * DD * 2);
    u16* wo_b = (u16*)alloc(L * DD * 2);
    u16* w1_b = (u16*)alloc(L * FD * 2);
    u16* w2_b = (u16*)alloc(L * FD * 2);
    u16* hw_b = (u16*)alloc((long)V * D * 2);
    float* qkvbias = (float*)alloc(L * 2304 * 4);
    float* h = (float*)alloc((long)M * D * 4);
    u16* a = (u16*)alloc((long)M * D * 2);
    u16* qkvb = (u16*)alloc((long)M * 2304 * 2);
    u16* vT = (u16*)alloc(24L * 64 * T * 2);
    u16* ctxb = (u16*)alloc((long)M * D * 2);
    u16* f1 = (u16*)alloc((long)M * F * 2);
    float* part = (float*)alloc(4L * PS * 4);

    auto cvt = [&](const float* src, u16* dst, long n, long chunk, long stride) {
        long blocks = (n + 1023) / 1024;
        if (blocks > 4096) blocks = 4096;
        cvt_kernel<<<dim3((unsigned)blocks), 256, 0, stream>>>(src, dst, n, chunk, stride);
    };
    cvt(wq, qkvw_b, L * DD, DD, 3 * DD);
    cvt(wk, qkvw_b + DD, L * DD, DD, 3 * DD);
    cvt(wv, qkvw_b + 2 * DD, L * DD, DD, 3 * DD);
    cvt(wo, wo_b, L * DD, L * DD, L * DD);
    cvt(w1, w1_b, L * FD, L * FD, L * FD);
    cvt(w2, w2_b, L * FD, L * FD, L * FD);
    cvt(headw, hw_b, (long)V * D, (long)V * D, (long)V * D);
    bias_fuse_kernel<<<dim3(18), 256, 0, stream>>>(bq, bk, bv, qkvbias);
    embed_ln_kernel<<<dim3(M), 256, 0, stream>>>(x, tok, pos, h, ln1w, ln1b, a);

    // cooperative 6-layer kernel (one dispatch, 42 grid barriers)
    LP lp;
    lp.qkvw = qkvw_b; lp.qkvbias = qkvbias;
    lp.a = a; lp.qkvb = qkvb; lp.vT = vT; lp.ctxb = ctxb; lp.f1 = f1;
    lp.wo = wo_b; lp.w1 = w1_b; lp.w2 = w2_b;
    lp.bo = bo; lp.b1 = b1; lp.b2 = b2;
    lp.ln2w = ln2w; lp.ln2b = ln2b; lp.ln1w = ln1w; lp.ln1b = ln1b;
    lp.lnfw = lnfw; lp.lnfb = lnfb;
    lp.h = h; lp.part = part;
    int nb = 0;
    hipOccupancyMaxActiveBlocksPerMultiprocessor(&nb, layers_kernel, 256, 0);
    if (nb < 1) nb = 1;
    int grid = nb * 256;
    if (grid > 768) grid = 768;
    void* kargs[] = {(void*)&lp};
    hipLaunchCooperativeKernel(layers_kernel, dim3(grid), dim3(256), kargs, 0, stream);

    // logits = a @ head_w^T -> f32 d_out
    gemmg_kernel<128, 128, 32, 5, 1><<<dim3(4000), 256, 0, stream>>>(
        a, D, hw_b, D, d_out, V, nullptr, D, 16, nullptr, 0);
}

// Round 17
// 960.246 us; speedup vs baseline: 3.7248x; 3.7248x over previous
//
#include <hip/hip_runtime.h>

typedef unsigned short u16;
typedef __bf16 bf16x8 __attribute__((ext_vector_type(8)));
typedef float f32x4 __attribute__((ext_vector_type(4)));
typedef float f32x4v __attribute__((ext_vector_type(4)));
typedef u16 u16x4 __attribute__((ext_vector_type(4)));

__device__ __forceinline__ float bf2f(u16 u) {
    unsigned x = ((unsigned)u) << 16;
    return __builtin_bit_cast(float, x);
}
__device__ __forceinline__ u16 f2bf(float f) {
    unsigned x = __builtin_bit_cast(unsigned, f);
    unsigned r = (x + 0x7FFFu + ((x >> 16) & 1u)) >> 16;
    return (u16)r;
}

// ==== merged weight conversion: ALL weights in one grid-stride kernel ====
// Virtual concatenation: [qkv interleave 3*L*DD][wo L*DD][w1 L*FD][w2 L*FD][head V*D]
__global__ __launch_bounds__(256) void cvt_all_kernel(
    const float* __restrict__ wq, const float* __restrict__ wk,
    const float* __restrict__ wv, const float* __restrict__ wo,
    const float* __restrict__ w1, const float* __restrict__ w2,
    const float* __restrict__ hw,
    u16* __restrict__ qkvw_b, u16* __restrict__ wo_b,
    u16* __restrict__ w1_b, u16* __restrict__ w2_b, u16* __restrict__ hw_b) {
    const long DD = 589824, FD = 2359296;
    const long N0 = 3 * 6 * DD;            // qkv region
    const long N1 = N0 + 6 * DD;           // + wo
    const long N2 = N1 + 6 * FD;           // + w1
    const long N3 = N2 + 6 * FD;           // + w2
    const long N4 = N3 + 24576000L;        // + head
    for (long i = (long)blockIdx.x * 1024 + (long)threadIdx.x * 4; i < N4;
         i += (long)gridDim.x * 1024) {
        const float* src;
        u16* dst;
        if (i < N0) {
            long layer = i / (3 * DD);
            long rem = i - layer * 3 * DD;
            long which = rem / DD;
            long off = rem - which * DD;
            src = (which == 0 ? wq : (which == 1 ? wk : wv)) + layer * DD + off;
            dst = qkvw_b + i;              // fused layout == region layout
        } else if (i < N1) {
            src = wo + (i - N0); dst = wo_b + (i - N0);
        } else if (i < N2) {
            src = w1 + (i - N1); dst = w1_b + (i - N1);
        } else if (i < N3) {
            src = w2 + (i - N2); dst = w2_b + (i - N2);
        } else {
            src = hw + (i - N3); dst = hw_b + (i - N3);
        }
        f32x4v v = *(const f32x4v*)src;
        u16x4 o;
        o.x = f2bf(v.x); o.y = f2bf(v.y); o.z = f2bf(v.z); o.w = f2bf(v.w);
        *(u16x4*)dst = o;
    }
}

// ---------------- fused qkv bias ----------------
__global__ __launch_bounds__(256) void bias_fuse_kernel(const float* __restrict__ bq,
                                                        const float* __restrict__ bk,
                                                        const float* __restrict__ bv,
                                                        float* __restrict__ dst) {
    int i = blockIdx.x * 256 + threadIdx.x;
    if (i < 6 * 768) {
        int l = i / 768, j = i % 768;
        dst[l * 2304 + j] = bq[i];
        dst[l * 2304 + 768 + j] = bk[i];
        dst[l * 2304 + 1536 + j] = bv[i];
    }
}

// ------- embed + layer-0 ln1 fused: h = tok[x]+pos; a = LN(h) -------
__global__ __launch_bounds__(256) void embed_ln_kernel(
    const int* __restrict__ x, const float* __restrict__ tok,
    const float* __restrict__ pos, float* __restrict__ h,
    const float* __restrict__ w, const float* __restrict__ b,
    u16* __restrict__ out) {
    __shared__ float red[4];
    int row = blockIdx.x;
    int t = row & 1023;
    long id = x[row];
    const float* te = tok + id * 768L;
    const float* pe = pos + (long)t * 768L;
    float* hr = h + (long)row * 768L;
    int tid = threadIdx.x, lane = tid & 63, wid = tid >> 6;
    float v0 = te[tid] + pe[tid];
    float v1 = te[tid + 256] + pe[tid + 256];
    float v2 = te[tid + 512] + pe[tid + 512];
    hr[tid] = v0; hr[tid + 256] = v1; hr[tid + 512] = v2;
    float s = v0 + v1 + v2;
    for (int o = 32; o; o >>= 1) s += __shfl_xor(s, o);
    if (lane == 0) red[wid] = s;
    __syncthreads();
    float mean = (red[0] + red[1] + red[2] + red[3]) * (1.f / 768.f);
    __syncthreads();
    float d0 = v0 - mean, d1 = v1 - mean, d2 = v2 - mean;
    float q = d0 * d0 + d1 * d1 + d2 * d2;
    for (int o = 32; o; o >>= 1) q += __shfl_xor(q, o);
    if (lane == 0) red[wid] = q;
    __syncthreads();
    float var = (red[0] + red[1] + red[2] + red[3]) * (1.f / 768.f);
    float rstd = rsqrtf(var + 1e-5f);
    u16* orow = out + (long)row * 768L;
    orow[tid]       = f2bf(d0 * rstd * w[tid]       + b[tid]);
    orow[tid + 256] = f2bf(d1 * rstd * w[tid + 256] + b[tid + 256]);
    orow[tid + 512] = f2bf(d2 * rstd * w[tid + 512] + b[tid + 512]);
}

// ------ redln (192 thr, f32x4): h += sum(partials)+bias; LN(h) -> a ------
__global__ __launch_bounds__(192) void redln_kernel(
    const float* __restrict__ part, long pstride, int S,
    const float* __restrict__ bias, float* __restrict__ h,
    const float* __restrict__ w, const float* __restrict__ b,
    u16* __restrict__ out) {
    __shared__ float red[3];
    int row = blockIdx.x;
    int tid = threadIdx.x, lane = tid & 63, wid = tid >> 6;
    long base = (long)row * 768 + tid * 4;
    f32x4v x = *(const f32x4v*)(h + base);
    f32x4v bb = *(const f32x4v*)(bias + tid * 4);
    x += bb;
    for (int s = 0; s < S; s++) x += *(const f32x4v*)(part + (long)s * pstride + base);
    *(f32x4v*)(h + base) = x;
    float s = x.x + x.y + x.z + x.w;
    for (int o = 32; o; o >>= 1) s += __shfl_xor(s, o);
    if (lane == 0) red[wid] = s;
    __syncthreads();
    float mean = (red[0] + red[1] + red[2]) * (1.f / 768.f);
    __syncthreads();
    f32x4v d = x - mean;
    float q = d.x * d.x + d.y * d.y + d.z * d.z + d.w * d.w;
    for (int o = 32; o; o >>= 1) q += __shfl_xor(q, o);
    if (lane == 0) red[wid] = q;
    __syncthreads();
    float var = (red[0] + red[1] + red[2]) * (1.f / 768.f);
    float rstd = rsqrtf(var + 1e-5f);
    f32x4v wv = *(const f32x4v*)(w + tid * 4);
    f32x4v bv = *(const f32x4v*)(b + tid * 4);
    u16x4 o;
    o.x = f2bf(d.x * rstd * wv.x + bv.x);
    o.y = f2bf(d.y * rstd * wv.y + bv.y);
    o.z = f2bf(d.z * rstd * wv.z + bv.z);
    o.w = f2bf(d.w * rstd * wv.w + bv.w);
    *(u16x4*)(out + base) = o;
}

// ---------------- flash attention (causal, DK=64, K/V double-buffered) ------
__global__ __launch_bounds__(256) void flash_kernel(
    const u16* __restrict__ qkv,   // [2048][2304]; q col 0, k col 768
    const u16* __restrict__ vT,    // [24][64][1024]
    u16* __restrict__ ctx) {       // [2048][768]
    int z = blockIdx.z;
    int zb = z / 12, zh = z - zb * 12;
    int qt = (int)gridDim.x - 1 - (int)blockIdx.x;  // big tiles first
    int q0 = qt * 64;
    int tid = threadIdx.x, lane = tid & 63, wid = tid >> 6;
    int rA = lane & 15, sA = lane >> 4;

    const u16* Qbase = qkv + (long)zb * 1024 * 2304 + zh * 64;
    const u16* Kbase = Qbase + 768;
    const u16* Vbase = vT + (long)z * 64 * 1024;

    __shared__ u16 Ks[2][64 * 64];
    __shared__ u16 Vs[2][64 * 64];
    __shared__ u16 Ps[4][16 * 64];

    bf16x8 aq[2];
    {
        const u16* qrow = Qbase + (long)(q0 + wid * 16 + rA) * 2304;
        aq[0] = *(const bf16x8*)(qrow + sA * 8);
        aq[1] = *(const bf16x8*)(qrow + 32 + sA * 8);
    }

    auto stage = [&](int buf, int kv0) {
#pragma unroll
        for (int c0 = 0; c0 < 512; c0 += 256) {
            int c = c0 + tid;
            int row = c >> 3, half = (c >> 2) & 1, sl = c & 3;
            int ks = sl ^ ((row >> 1) & 3);
            __builtin_amdgcn_global_load_lds(
                (const __attribute__((address_space(1))) unsigned*)(Kbase + (long)(kv0 + row) * 2304 + half * 32 + ks * 8),
                (__attribute__((address_space(3))) unsigned*)(Ks[buf] + c * 8), 16, 0, 0);
        }
#pragma unroll
        for (int c0 = 0; c0 < 512; c0 += 256) {
            int c = c0 + tid;
            int row = c >> 3, half = (c >> 2) & 1, sl = c & 3;
            int ks = sl ^ ((row >> 1) & 3);
            __builtin_amdgcn_global_load_lds(
                (const __attribute__((address_space(1))) unsigned*)(Vbase + (long)row * 1024 + kv0 + half * 32 + ks * 8),
                (__attribute__((address_space(3))) unsigned*)(Vs[buf] + c * 8), 16, 0, 0);
        }
    };

    float m[4], l[4];
    f32x4 acc_o[4];
#pragma unroll
    for (int j = 0; j < 4; j++) { m[j] = -1e30f; l[j] = 0.f; }
#pragma unroll
    for (int nf = 0; nf < 4; nf++) acc_o[nf] = 0.f;

    int grow0 = q0 + wid * 16 + sA * 4;
    int nkv = qt + 1;

    stage(0, 0);
    __syncthreads();
    for (int t = 0; t < nkv; ++t) {
        int cur = t & 1;
        int kv0 = t * 64;
        if (t + 1 < nkv) stage(cur ^ 1, (t + 1) * 64);

        f32x4 s[4];
#pragma unroll
        for (int nf = 0; nf < 4; nf++) s[nf] = 0.f;
        __builtin_amdgcn_s_setprio(1);
#pragma unroll
        for (int h = 0; h < 2; h++)
#pragma unroll
            for (int nf = 0; nf < 4; nf++) {
                int row = nf * 16 + rA;
                bf16x8 bk_ = *(const bf16x8*)(Ks[cur] + row * 64 + h * 32 + ((sA ^ ((row >> 1) & 3))) * 8);
                s[nf] = __builtin_amdgcn_mfma_f32_16x16x32_bf16(aq[h], bk_, s[nf], 0, 0, 0);
            }
        __builtin_amdgcn_s_setprio(0);
#pragma unroll
        for (int nf = 0; nf < 4; nf++) {
            int col = kv0 + nf * 16 + rA;
#pragma unroll
            for (int j = 0; j < 4; j++)
                s[nf][j] = (col <= grow0 + j) ? s[nf][j] * 0.125f : -1e30f;
        }
        float pm[4];
#pragma unroll
        for (int j = 0; j < 4; j++) {
            float v = fmaxf(fmaxf(s[0][j], s[1][j]), fmaxf(s[2][j], s[3][j]));
#pragma unroll
            for (int o = 1; o < 16; o <<= 1) v = fmaxf(v, __shfl_xor(v, o));
            pm[j] = v;
        }
        float esc[4];
#pragma unroll
        for (int j = 0; j < 4; j++) {
            float mn = fmaxf(m[j], pm[j]);
            esc[j] = __expf(m[j] - mn);
            m[j] = mn;
        }
        float ts[4] = {0.f, 0.f, 0.f, 0.f};
#pragma unroll
        for (int nf = 0; nf < 4; nf++) {
            int c = nf * 16 + rA;
            int half = c >> 5, ch = (c >> 3) & 3, e = c & 7;
#pragma unroll
            for (int j = 0; j < 4; j++) {
                float p = __expf(s[nf][j] - m[j]);
                ts[j] += p;
                int r = sA * 4 + j;
                Ps[wid][r * 64 + half * 32 + (ch ^ ((r >> 1) & 3)) * 8 + e] = f2bf(p);
            }
        }
#pragma unroll
        for (int j = 0; j < 4; j++) {
            float v = ts[j];
#pragma unroll
            for (int o = 1; o < 16; o <<= 1) v += __shfl_xor(v, o);
            l[j] = l[j] * esc[j] + v;
        }
#pragma unroll
        for (int nf = 0; nf < 4; nf++)
#pragma unroll
            for (int j = 0; j < 4; j++) acc_o[nf][j] *= esc[j];

        __builtin_amdgcn_s_setprio(1);
#pragma unroll
        for (int h = 0; h < 2; h++) {
            bf16x8 ap = *(const bf16x8*)(Ps[wid] + rA * 64 + h * 32 + ((sA ^ ((rA >> 1) & 3))) * 8);
#pragma unroll
            for (int nf = 0; nf < 4; nf++) {
                int row = nf * 16 + rA;
                bf16x8 bv_ = *(const bf16x8*)(Vs[cur] + row * 64 + h * 32 + ((sA ^ ((row >> 1) & 3))) * 8);
                acc_o[nf] = __builtin_amdgcn_mfma_f32_16x16x32_bf16(ap, bv_, acc_o[nf], 0, 0, 0);
            }
        }
        __builtin_amdgcn_s_setprio(0);
        __syncthreads();  // drains stage(t+1); protects buffers for next iter
    }

    float inv[4];
#pragma unroll
    for (int j = 0; j < 4; j++) inv[j] = 1.f / l[j];
    u16* crow = ctx + ((long)zb * 1024 + q0 + wid * 16) * 768 + zh * 64;
#pragma unroll
    for (int nf = 0; nf < 4; nf++)
#pragma unroll
        for (int j = 0; j < 4; j++)
            crow[(long)(sA * 4 + j) * 768 + nf * 16 + rA] = f2bf(acc_o[nf][j] * inv[j]);
}

// ==== MFMA GEMM v8: 2-phase dbuf + swizzle, template BK, split-K ====
// EPI: 2 relu(+bias) bf16; 5 f32 (+slice*partStride); 6 qkv-split.
template <int BM, int BN, int BK, int EPI, int SK>
__global__ __launch_bounds__(256) void gemm8_kernel(
    const u16* __restrict__ A, int lda,
    const u16* __restrict__ Bm, int ldb,
    void* __restrict__ Cv, int ldc,
    const float* __restrict__ bias, int Kslice, int gm,
    u16* __restrict__ aux, long partStride) {
    constexpr int CPR = BK / 8;      // 16B chunks per row
    constexpr int KH = BK / 32;      // MFMA k-steps per tile
    int flat = blockIdx.x;
    int tid = threadIdx.x;
    int nwg = gridDim.x;
    int qq = nwg >> 3, rr = nwg & 7;
    int xcd = flat & 7, wi = flat >> 3;
    int swz = (xcd < rr) ? (xcd * (qq + 1) + wi) : (rr * (qq + 1) + (xcd - rr) * qq + wi);
    int slice = 0, wblk = swz;
    if (SK > 1) { int nbs = nwg / SK; slice = swz / nbs; wblk = swz - slice * nbs; }
    int ntile = wblk / gm, mt = wblk - ntile * gm;
    int bm0 = mt * BM, bn0 = ntile * BN;
    long koff = (long)slice * Kslice;
    const u16* Ab = A + (long)bm0 * lda + koff;
    const u16* Bb = Bm + (long)bn0 * ldb + koff;

    __shared__ u16 As[2][BM * BK];
    __shared__ u16 Bs[2][BN * BK];

    int lane = tid & 63, wid = tid >> 6;
    constexpr int WM = BM / 2, WN = BN / 2, MR = WM / 16, NR = WN / 16;
    int wm0 = (wid >> 1) * WM, wn0 = (wid & 1) * WN;

    f32x4 acc[MR][NR];
#pragma unroll
    for (int mi = 0; mi < MR; mi++)
#pragma unroll
        for (int ni = 0; ni < NR; ni++) acc[mi][ni] = 0.f;

    int nt = Kslice / BK;

    auto key = [](int row) { return (BK == 32) ? ((row >> 1) & 3) : (row & 7); };

    auto stage = [&](int buf, int k0) {
        constexpr int CA = BM * CPR;
#pragma unroll
        for (int c0 = 0; c0 < CA; c0 += 256) {
            int c = c0 + tid;
            int row = c / CPR, sl = c & (CPR - 1);
            int ks = sl ^ key(row);
            __builtin_amdgcn_global_load_lds(
                (const __attribute__((address_space(1))) unsigned*)(Ab + (long)row * lda + k0 + ks * 8),
                (__attribute__((address_space(3))) unsigned*)(As[buf] + c * 8), 16, 0, 0);
        }
        constexpr int CB = BN * CPR;
#pragma unroll
        for (int c0 = 0; c0 < CB; c0 += 256) {
            int c = c0 + tid;
            int row = c / CPR, sl = c & (CPR - 1);
            int ks = sl ^ key(row);
            __builtin_amdgcn_global_load_lds(
                (const __attribute__((address_space(1))) unsigned*)(Bb + (long)row * ldb + k0 + ks * 8),
                (__attribute__((address_space(3))) unsigned*)(Bs[buf] + c * 8), 16, 0, 0);
        }
    };

    stage(0, 0);
    __syncthreads();
    int cur = 0;
    int rA = lane & 15, sA = lane >> 4;
    for (int t = 0; t < nt; ++t) {
        if (t + 1 < nt) stage(cur ^ 1, (t + 1) * BK);
        bf16x8 af[MR][KH], bfr[NR][KH];
#pragma unroll
        for (int mi = 0; mi < MR; mi++) {
            int row = wm0 + mi * 16 + rA;
#pragma unroll
            for (int h = 0; h < KH; h++)
                af[mi][h] = *(const bf16x8*)(As[cur] + row * BK + (((h << 2) + sA) ^ key(row)) * 8);
        }
#pragma unroll
        for (int ni = 0; ni < NR; ni++) {
            int row = wn0 + ni * 16 + rA;
#pragma unroll
            for (int h = 0; h < KH; h++)
                bfr[ni][h] = *(const bf16x8*)(Bs[cur] + row * BK + (((h << 2) + sA) ^ key(row)) * 8);
        }
#pragma unroll
        for (int h = 0; h < KH; h++)
#pragma unroll
            for (int mi = 0; mi < MR; mi++)
#pragma unroll
                for (int ni = 0; ni < NR; ni++)
                    acc[mi][ni] = __builtin_amdgcn_mfma_f32_16x16x32_bf16(
                        af[mi][h], bfr[ni][h], acc[mi][ni], 0, 0, 0);
        __syncthreads();
        cur ^= 1;
    }

#pragma unroll
    for (int mi = 0; mi < MR; mi++)
#pragma unroll
        for (int ni = 0; ni < NR; ni++) {
            int gmb = bm0 + wm0 + mi * 16 + ((lane >> 4) << 2);
            int gn = bn0 + wn0 + ni * 16 + (lane & 15);
            if (EPI == 6) {
                if (gn < 1536) {
#pragma unroll
                    for (int j = 0; j < 4; j++)
                        ((u16*)Cv)[(long)(gmb + j) * ldc + gn] =
                            f2bf(acc[mi][ni][j] + bias[gn]);
                } else {
                    u16x4 o;
#pragma unroll
                    for (int j = 0; j < 4; j++) o[j] = f2bf(acc[mi][ni][j] + bias[gn]);
                    int hh = (gn - 1536) >> 6, dk = gn & 63;
                    long off = ((long)((gmb >> 10) * 12 + hh) * 64 + dk) * 1024 + (gmb & 1023);
                    *(u16x4*)(aux + off) = o;
                }
            } else {
#pragma unroll
                for (int j = 0; j < 4; j++) {
                    float v = acc[mi][ni][j];
                    long idx = (long)(gmb + j) * ldc + gn;
                    if (EPI == 2) ((u16*)Cv)[idx] = f2bf(fmaxf(v + bias[gn], 0.f));
                    else ((float*)Cv)[(long)slice * partStride + idx] = v;  // EPI 5
                }
            }
        }
}

// ---------------- host side ----------------
extern "C" void kernel_launch(void* const* d_in, const int* in_sizes, int n_in,
                              void* d_out, int out_size, void* d_ws, size_t ws_size,
                              hipStream_t stream) {
    const int L = 6, D = 768, F = 3072, T = 1024, V = 32000;
    const int M = 2048;  // B*T
    const int* x = (const int*)d_in[0];
    const float* tok = (const float*)d_in[1];
    const float* pos = (const float*)d_in[2];
    const float* ln1w = (const float*)d_in[3];
    const float* ln1b = (const float*)d_in[4];
    const float* wq = (const float*)d_in[5];
    const float* bq = (const float*)d_in[6];
    const float* wk = (const float*)d_in[7];
    const float* bk = (const float*)d_in[8];
    const float* wv = (const float*)d_in[9];
    const float* bv = (const float*)d_in[10];
    const float* wo = (const float*)d_in[11];
    const float* bo = (const float*)d_in[12];
    const float* ln2w = (const float*)d_in[13];
    const float* ln2b = (const float*)d_in[14];
    const float* w1 = (const float*)d_in[15];
    const float* b1 = (const float*)d_in[16];
    const float* w2 = (const float*)d_in[17];
    const float* b2 = (const float*)d_in[18];
    const float* lnfw = (const float*)d_in[19];
    const float* lnfb = (const float*)d_in[20];
    const float* headw = (const float*)d_in[21];

    char* p = (char*)d_ws;
    auto alloc = [&](size_t bytes) {
        char* r = p;
        p += (bytes + 255) & ~(size_t)255;
        return r;
    };
    const long DD = (long)D * D, FD = (long)F * D;
    const long PS = (long)M * D;                 // partial stride (f32 elems)
    u16* qkvw_b = (u16*)alloc(L * 3 * DD * 2);   // [L][2304][768] fused
    u16* wo_b = (u16*)alloc(L * DD * 2);
    u16* w1_b = (u16*)alloc(L * FD * 2);
    u16* w2_b = (u16*)alloc(L * FD * 2);
    u16* hw_b = (u16*)alloc((long)V * D * 2);
    float* qkvbias = (float*)alloc(L * 2304 * 4);
    float* h = (float*)alloc((long)M * D * 4);
    u16* a = (u16*)alloc((long)M * D * 2);
    u16* qkvb = (u16*)alloc((long)M * 2304 * 2);
    u16* vT = (u16*)alloc(24L * 64 * T * 2);     // [B*H][64][T]
    u16* ctxb = (u16*)alloc((long)M * D * 2);
    u16* f1 = (u16*)alloc((long)M * F * 2);
    float* part = (float*)alloc(4L * PS * 4);    // split-K partials [4][2048][768]

    // single merged conversion pass over all weights
    cvt_all_kernel<<<dim3(4096), 256, 0, stream>>>(
        wq, wk, wv, wo, w1, w2, headw, qkvw_b, wo_b, w1_b, w2_b, hw_b);
    bias_fuse_kernel<<<dim3(18), 256, 0, stream>>>(bq, bk, bv, qkvbias);
    // fused embed + layer-0 ln1
    embed_ln_kernel<<<dim3(M), 256, 0, stream>>>(x, tok, pos, h, ln1w, ln1b, a);

    for (int i = 0; i < L; i++) {
        int nx = i + 1;
        bool hn = nx < L;
        // qkv = a @ qkvw^T + bias ; v -> vT. 64x128 BK=64, 12 steps.
        gemm8_kernel<64, 128, 64, 6, 1><<<dim3(576), 256, 0, stream>>>(
            a, D, qkvw_b + i * 3 * DD, D, qkvb, 2304, qkvbias + i * 2304,
            D, 32, vT, 0);
        flash_kernel<<<dim3(16, 1, 24), 256, 0, stream>>>(qkvb, vT, ctxb);
        // wo split-K=2 (Kslice=384, 6 steps) -> partials
        gemm8_kernel<64, 128, 64, 5, 2><<<dim3(384), 256, 0, stream>>>(
            ctxb, D, wo_b + i * DD, D, part, D, nullptr, 384, 32, nullptr, PS);
        // h += p0+p1 + bo ; a = LN(h, ln2)
        redln_kernel<<<dim3(M), 192, 0, stream>>>(
            part, PS, 2, bo + i * D, h, ln2w + i * D, ln2b + i * D, a);
        // f1 = relu(a @ w1^T + b1). 64x128 BK=64, 12 steps.
        gemm8_kernel<64, 128, 64, 2, 1><<<dim3(768), 256, 0, stream>>>(
            a, D, w1_b + i * FD, D, f1, F, b1 + i * F, D, 32, nullptr, 0);
        // ffn2 split-K=4 (Kslice=768, 12 steps) -> partials
        gemm8_kernel<64, 128, 64, 5, 4><<<dim3(768), 256, 0, stream>>>(
            f1, F, w2_b + i * FD, F, part, D, nullptr, 768, 32, nullptr, PS);
        // h += p0..p3 + b2 ; a = LN(h, next ln1 or lnf)
        redln_kernel<<<dim3(M), 192, 0, stream>>>(
            part, PS, 4, b2 + i * D, h,
            hn ? ln1w + nx * D : lnfw, hn ? ln1b + nx * D : lnfb, a);
    }
    // logits = a @ head_w^T -> f32 d_out (128x128 BK=32, best-measured)
    gemm8_kernel<128, 128, 32, 5, 1><<<dim3(4000), 256, 0, stream>>>(
        a, D, hw_b, D, d_out, V, nullptr, D, 16, nullptr, 0);
}